// Round 9
// baseline (439.198 us; speedup 1.0000x reference)
//
#include <hip/hip_runtime.h>
#include <stdint.h>

typedef unsigned short u16;
typedef unsigned int u32;
typedef unsigned long long u64;
typedef __attribute__((ext_vector_type(8))) short short8;
typedef __attribute__((ext_vector_type(4))) float floatx4;

#define DIM 128
#define DIM2 64     // h dwords per row (2 bf16 per dword)
#define NBK 1792    // scatter scan width >= B = ceil(N/64) = 1563
#define NB_SH 6     // 64 nodes per bucket
#define AGG_NB 64
#define AGG_CAP 2560  // max staged records/bucket (mean 2048, std 45 -> +11 sigma)
#define SC_C 12800    // edges per scatter region (E/12800 = 250 exactly)
#define NSEG 256      // segment-directory capacity >= nsc = 250

__device__ __forceinline__ u32 f32_to_bf16_rne(float f) {
  u32 u = __float_as_uint(f);
  u32 r = u + 0x7fffu + ((u >> 16) & 1u);
  return r >> 16;
}
__device__ __forceinline__ float bf16_to_f32(u32 u) { return __uint_as_float(u << 16); }
__device__ __forceinline__ u32 pack2bf16(float a, float b) {
  return f32_to_bf16_rne(a) | (f32_to_bf16_rne(b) << 16);
}

union FragU {
  u32 d[4];
  short8 s;
};

// h = x @ W^T via bf16 MFMA (unchanged; frag maps verified m89/m120).
__global__ __launch_bounds__(256) void gemm_mfma(const float* __restrict__ x,
                                                 const float* __restrict__ W,
                                                 u16* __restrict__ h, int N) {
  __shared__ u32 Wl[DIM * DIM2];  // 32 KB
  int tid = threadIdx.x;
#pragma unroll
  for (int i = 0; i < 8; ++i) {
    int ga = tid + 256 * i;
    int o = ga >> 4, g = ga & 15;
    const float* src = W + (size_t)o * DIM + g * 8;
    floatx4 f0 = *(const floatx4*)src;
    floatx4 f1 = *(const floatx4*)(src + 4);
    int slot = (g + o) & 15;
    u32* dst = &Wl[o * DIM2 + slot * 4];
    dst[0] = pack2bf16(f0.x, f0.y);
    dst[1] = pack2bf16(f0.z, f0.w);
    dst[2] = pack2bf16(f1.x, f1.y);
    dst[3] = pack2bf16(f1.z, f1.w);
  }
  __syncthreads();

  int lane = tid & 63;
  int wave = tid >> 6;
  int m = lane & 15;
  int kg = lane >> 4;
  int ntile = (N + 63) >> 6;  // 64-node tiles

  for (int t = blockIdx.x; t < ntile; t += 256) {
    int nodeBase = t * 64 + wave * 16;
    if (nodeBase >= N) continue;

    short8 a[4];
    const float* xr = x + (size_t)(nodeBase + m) * DIM + kg * 8;
#pragma unroll
    for (int kt = 0; kt < 4; ++kt) {
      floatx4 f0 = *(const floatx4*)(xr + kt * 32);
      floatx4 f1 = *(const floatx4*)(xr + kt * 32 + 4);
      FragU fu;
      fu.d[0] = pack2bf16(f0.x, f0.y);
      fu.d[1] = pack2bf16(f0.z, f0.w);
      fu.d[2] = pack2bf16(f1.x, f1.y);
      fu.d[3] = pack2bf16(f1.z, f1.w);
      a[kt] = fu.s;
    }

#pragma unroll
    for (int ot = 0; ot < 8; ++ot) {
      int o = ot * 16 + m;
      floatx4 acc = {0.f, 0.f, 0.f, 0.f};
#pragma unroll
      for (int kt = 0; kt < 4; ++kt) {
        int slot = (kt * 4 + kg + o) & 15;
        short8 b = *(short8*)&Wl[o * DIM2 + slot * 4];
        acc = __builtin_amdgcn_mfma_f32_16x16x32_bf16(a[kt], b, acc, 0, 0, 0);
      }
#pragma unroll
      for (int r = 0; r < 4; ++r) {
        int node = nodeBase + kg * 4 + r;
        h[(size_t)node * DIM + ot * 16 + m] = (u16)f32_to_bf16_rne(acc[r]);
      }
    }
  }
}

// Region-local sort-scatter v3: 1024 threads (16 waves/CU vs R8's 4), NO LDS
// record staging — rank-and-write DIRECTLY into the region's own 64 KB global
// window (stays L2-resident, lines fully covered -> write amp ~1; R0's
// pathology was a 19 MB window). LDS = hist+starts only (14 KB).
__global__ __launch_bounds__(1024) void sort_scatter(const int* __restrict__ rows,
                                                     const int* __restrict__ cols,
                                                     const float* __restrict__ vals,
                                                     u32* __restrict__ bcol,
                                                     u16* __restrict__ bval,
                                                     u32* __restrict__ dirT, int E, int B,
                                                     int nsc) {
  __shared__ u32 hist[NBK];    // counts -> running ptr
  __shared__ u32 starts[NBK];  // exclusive scan
  __shared__ u32 wtot[16];
  int tid = threadIdx.x, lane = tid & 63, wv = tid >> 6;
  int wg = blockIdx.x;
  int base = wg * SC_C;
  int tot = min(SC_C, E - base);

  for (int b = tid; b < NBK; b += 1024) hist[b] = 0;
  __syncthreads();
  // pass 1: local bucket histogram
  for (int j = tid; j < tot; j += 1024) {
    atomicAdd(&hist[((u32)rows[base + j]) >> NB_SH], 1u);
  }
  __syncthreads();
  // scan 1792 counters with 1024 threads (2 contiguous per thread)
  {
    int i0 = tid * 2;
    u32 c0 = (i0 < NBK) ? hist[i0] : 0u;
    u32 c1 = (i0 + 1 < NBK) ? hist[i0 + 1] : 0u;
    u32 sum = c0 + c1, inc = sum;
#pragma unroll
    for (int d = 1; d < 64; d <<= 1) {
      u32 t = __shfl_up(inc, d, 64);
      if (lane >= d) inc += t;
    }
    if (lane == 63) wtot[wv] = inc;
    __syncthreads();
    u32 wbase = 0;
    for (int w = 0; w < wv; ++w) wbase += wtot[w];
    u32 ex = wbase + inc - sum;
    if (i0 < NBK) {
      starts[i0] = ex;
      hist[i0] = ex;  // running ptr
    }
    if (i0 + 1 < NBK) {
      starts[i0 + 1] = ex + c0;
      hist[i0 + 1] = ex + c0;
    }
    __syncthreads();
  }
  // pass 2: rank + direct region-local global writes
  for (int j = tid; j < tot; j += 1024) {
    u32 r = (u32)rows[base + j];
    u32 bk = r >> NB_SH;
    u32 p = atomicAdd(&hist[bk], 1u);
    bcol[(size_t)base + p] = ((r & 63u) << 26) | ((u32)cols[base + j] << 8);
    bval[(size_t)base + p] = (u16)f32_to_bf16_rne(vals[base + j]);
  }
  __syncthreads();
  // transposed directory: dirT[b][wg] = (start<<16)|cnt
  for (int b = tid; b < B; b += 1024) {
    dirT[(size_t)b * nsc + wg] = (starts[b] << 16) | (hist[b] - starts[b]);
  }
}

// One WG per 64-node bucket. LDS cut to ~18 KB (8 WG/CU, vs R8's 28.7 KB /
// 5 WG/CU): no map (per-thread CONSECUTIVE records: 1 binary search + forward
// walk), s_rec u64 split into s_lo u32 + s_v u16. Pass C = proven flat walk
// with depth-8 gather pipeline + direct relu'd global flush.
__global__ __launch_bounds__(256) void agg_bucket(const u32* __restrict__ bcol,
                                                  const u16* __restrict__ bval,
                                                  const u32* __restrict__ dirT,
                                                  const u32* __restrict__ h,
                                                  float* __restrict__ out, int N,
                                                  int nsc, int B) {
  __shared__ u32 s_lo[AGG_CAP];  // 10 KB
  __shared__ u16 s_v[AGG_CAP];   // 5 KB
  __shared__ u32 segdir[NSEG], segdst[NSEG];  // 2 KB
  __shared__ u32 cnt[AGG_NB], excl[AGG_NB], ptr[AGG_NB];
  __shared__ u32 sT;
  int tid = threadIdx.x, lane = tid & 63, wave = tid >> 6;
  int b = blockIdx.x;
  int nodeBase = b << NB_SH;
  int lane4 = lane * 4;
  const char* hb = (const char*)h;

  // coalesced directory row + zero node counters
  for (int w = tid; w < NSEG; w += 256)
    segdir[w] = (w < nsc) ? dirT[(size_t)b * nsc + w] : 0u;
  if (tid < AGG_NB) cnt[tid] = 0;
  __syncthreads();
  // exclusive scan of 256 segment counts with one wave (4 per lane);
  // padding entries (cnt 0) get segdst = T, which terminates the walk.
  if (tid < 64) {
    u32 c[4], sum = 0;
#pragma unroll
    for (int k = 0; k < 4; ++k) {
      c[k] = segdir[lane * 4 + k] & 0xffffu;
      sum += c[k];
    }
    u32 inc = sum;
#pragma unroll
    for (int d = 1; d < 64; d <<= 1) {
      u32 t = __shfl_up(inc, d, 64);
      if (lane >= d) inc += t;
    }
    u32 run = inc - sum;
#pragma unroll
    for (int k = 0; k < 4; ++k) {
      segdst[lane * 4 + k] = run;
      run += c[k];
    }
    if (lane == 63) sT = inc;
  }
  __syncthreads();
  int T = (int)sT;

  if (T <= AGG_CAP) {
    // pass A: per-thread npt CONSECUTIVE records; one 8-step binary search
    // for the first record's segment, then forward walk. Per-thread loads
    // are sequential within segments.
    int npt = (T + 255) >> 8;  // <= 10
    int g0 = tid * npt;
    int gend = min(g0 + npt, T);
    u32 rlo[10], rv[10];
    int sw = 0;
    u32 swst = 0, swcnt = 0;
    if (g0 < T) {
      int lo = 0, hi = NSEG - 1;
#pragma unroll
      for (int s = 0; s < 8; ++s) {
        int mid = (lo + hi + 1) >> 1;
        if (segdst[mid] <= (u32)g0) lo = mid; else hi = mid - 1;
      }
      sw = lo;
      swst = segdst[sw];
      swcnt = segdir[sw] & 0xffffu;
    }
#pragma unroll
    for (int k = 0; k < 10; ++k) {
      rlo[k] = 0;
      rv[k] = 0;
      int g = g0 + k;
      if (g < gend) {
        while ((u32)g >= swst + swcnt) {  // advance (skips empty segments)
          ++sw;
          swst = segdst[sw];
          swcnt = segdir[sw] & 0xffffu;
        }
        u32 src = (u32)sw * SC_C + (segdir[sw] >> 16) + ((u32)g - swst);
        rlo[k] = bcol[src];
        rv[k] = bval[src];
        atomicAdd(&cnt[rlo[k] >> 26], 1u);
      }
    }
    __syncthreads();
    // scan 64 node counters (wave 0)
    if (tid < 64) {
      u32 c = cnt[tid], inc = c;
#pragma unroll
      for (int d = 1; d < 64; d <<= 1) {
        u32 t = __shfl_up(inc, d, 64);
        if (lane >= d) inc += t;
      }
      excl[tid] = inc - c;
      ptr[tid] = inc - c;
    }
    __syncthreads();
    // pass B: rank into node-sorted LDS staging
#pragma unroll
    for (int k = 0; k < 10; ++k) {
      int g = g0 + k;
      if (g < gend) {
        u32 p = atomicAdd(&ptr[rlo[k] >> 26], 1u);
        s_lo[p] = rlo[k];
        s_v[p] = (u16)rv[k];
      }
    }
    __syncthreads();
    // pass C: flat walk of my wave's 16 nodes' contiguous segment
    int wbeg = (int)excl[wave * 16];
    int wend = (int)ptr[wave * 16 + 15];
    float a0 = 0.f, a1 = 0.f;
    int curn = -1;
    for (int e = wbeg; e < wend; e += 8) {
      u32 lo8[8];
      float v8[8];
      u32 hd[8];
#pragma unroll
      for (int g = 0; g < 8; ++g) {
        int ee = e + g;
        bool act = ee < wend;
        int idx = act ? ee : (wend - 1);  // wave-uniform broadcast reads
        lo8[g] = s_lo[idx];
        v8[g] = act ? bf16_to_f32((u32)s_v[idx]) : 0.f;
      }
#pragma unroll
      for (int g = 0; g < 8; ++g) {
        hd[g] = *(const u32*)(hb + ((lo8[g] & 0x01FFFF00u) + lane4));
      }
#pragma unroll
      for (int g = 0; g < 8; ++g) {
        int nid = __builtin_amdgcn_readfirstlane((int)(lo8[g] >> 26));
        if (nid != curn) {  // scalar branch, once per run
          if (curn >= 0) {
            float2 o = make_float2(fmaxf(a0, 0.f), fmaxf(a1, 0.f));
            *(float2*)(out + (size_t)(nodeBase + curn) * DIM + 2 * lane) = o;
          }
          curn = nid;
          a0 = 0.f;
          a1 = 0.f;
        }
        float v = v8[g];
        a0 += v * bf16_to_f32(hd[g] & 0xffffu);
        a1 += v * bf16_to_f32(hd[g] >> 16);
      }
    }
    if (curn >= 0) {
      float2 o = make_float2(fmaxf(a0, 0.f), fmaxf(a1, 0.f));
      *(float2*)(out + (size_t)(nodeBase + curn) * DIM + 2 * lane) = o;
    }
    // epilogue: zero rows for nodes with no edges
    for (int nn = 0; nn < 16; ++nn) {
      int nl = wave * 16 + nn;
      int node = nodeBase + nl;
      if (cnt[nl] == 0 && node < N) {
        *(float2*)(out + (size_t)node * DIM + 2 * lane) = make_float2(0.f, 0.f);
      }
    }
  } else {
    // Guaranteed-correct fallback (statistically unreachable): per-node scan
    // of all this bucket's segments.
    for (int nn = 0; nn < 16; ++nn) {
      int nl = wave * 16 + nn;
      int node = nodeBase + nl;
      if (node >= N) continue;
      float a0 = 0.f, a1 = 0.f;
      for (int w = 0; w < nsc; ++w) {
        u32 dv = segdir[w];
        int sc = (int)(dv & 0xffffu);
        u32 so = dv >> 16;
        for (int r = 0; r < sc; ++r) {
          u32 lo = bcol[(size_t)w * SC_C + so + r];
          if ((int)(lo >> 26) == nl) {
            u32 d = *(const u32*)(hb + ((lo & 0x01FFFF00u) + lane4));
            float v = bf16_to_f32(bval[(size_t)w * SC_C + so + r]);
            a0 += v * bf16_to_f32(d & 0xffffu);
            a1 += v * bf16_to_f32(d >> 16);
          }
        }
      }
      *(float2*)(out + (size_t)node * DIM + 2 * lane) =
          make_float2(fmaxf(a0, 0.f), fmaxf(a1, 0.f));
    }
  }
}

extern "C" void kernel_launch(void* const* d_in, const int* in_sizes, int n_in,
                              void* d_out, int out_size, void* d_ws, size_t ws_size,
                              hipStream_t stream) {
  const float* x    = (const float*)d_in[0];  // fp32 [N,128]
  const int*   rows = (const int*)d_in[1];    // int32 [E]
  const int*   cols = (const int*)d_in[2];    // int32 [E]
  const float* vals = (const float*)d_in[3];  // fp32 [E]
  const float* W    = (const float*)d_in[4];  // fp32 [128,128]

  const int N = in_sizes[0] / DIM;  // 100000
  const int E = in_sizes[1];        // 3200000
  const int B = (N + AGG_NB - 1) / AGG_NB;  // 1563 buckets (64 nodes each)
  const int nsc = (E + SC_C - 1) / SC_C;    // 250 regions

  char* wsb = (char*)d_ws;
  size_t o = 0;
  u16* h = (u16*)wsb;            o += (size_t)N * DIM * sizeof(u16);      // 25.6 MB
  u32* bcol = (u32*)(wsb + o);   o += (size_t)nsc * SC_C * sizeof(u32);   // 12.8 MB
  u16* bval = (u16*)(wsb + o);   o += (size_t)nsc * SC_C * sizeof(u16);   // 6.4 MB
  u32* dirT = (u32*)(wsb + o);   o += (size_t)B * nsc * sizeof(u32);      // 1.56 MB

  gemm_mfma<<<256, 256, 0, stream>>>(x, W, h, N);
  sort_scatter<<<nsc, 1024, 0, stream>>>(rows, cols, vals, bcol, bval, dirT, E, B, nsc);
  agg_bucket<<<B, 256, 0, stream>>>(bcol, bval, dirT, (const u32*)h,
                                    (float*)d_out, N, nsc, B);
}

// Round 10
// 373.432 us; speedup vs baseline: 1.1761x; 1.1761x over previous
//
#include <hip/hip_runtime.h>
#include <stdint.h>

typedef unsigned short u16;
typedef unsigned int u32;
typedef unsigned long long u64;
typedef __attribute__((ext_vector_type(8))) short short8;
typedef __attribute__((ext_vector_type(4))) float floatx4;

#define DIM 128
#define DIM2 64     // h dwords per row (2 bf16 per dword)
#define NBK 2048    // scan width (max buckets); B = ceil(N/64) = 1563
#define NB_SH 6     // 64 nodes per bucket
#define AGG_NB 64
#define AGG_CAP 2560  // max staged records/bucket (mean 2048, std 45 -> +11 sigma)
#define SC_C 8192     // edges per scatter chunk
#define HIST_C 4096   // edges per hist workgroup chunk

__device__ __forceinline__ u32 f32_to_bf16_rne(float f) {
  u32 u = __float_as_uint(f);
  u32 r = u + 0x7fffu + ((u >> 16) & 1u);
  return r >> 16;
}
__device__ __forceinline__ float bf16_to_f32(u32 u) { return __uint_as_float(u << 16); }
__device__ __forceinline__ u32 pack2bf16(float a, float b) {
  return f32_to_bf16_rne(a) | (f32_to_bf16_rne(b) << 16);
}

union FragU {
  u32 d[4];
  short8 s;
};

// h = x @ W^T via bf16 MFMA. One 64-node tile per WG (1563 WGs): R0-R3 form,
// reverted from the 256-WG grid-stride (1 WG/CU = 12.5% occ, 6 serial tiles).
// W re-staging per WG is L2-resident and cheap.
__global__ __launch_bounds__(256) void gemm_mfma(const float* __restrict__ x,
                                                 const float* __restrict__ W,
                                                 u16* __restrict__ h, int N) {
  __shared__ u32 Wl[DIM * DIM2];  // 32 KB
  int tid = threadIdx.x;
#pragma unroll
  for (int i = 0; i < 8; ++i) {
    int ga = tid + 256 * i;
    int o = ga >> 4, g = ga & 15;
    const float* src = W + (size_t)o * DIM + g * 8;
    floatx4 f0 = *(const floatx4*)src;
    floatx4 f1 = *(const floatx4*)(src + 4);
    int slot = (g + o) & 15;
    u32* dst = &Wl[o * DIM2 + slot * 4];
    dst[0] = pack2bf16(f0.x, f0.y);
    dst[1] = pack2bf16(f0.z, f0.w);
    dst[2] = pack2bf16(f1.x, f1.y);
    dst[3] = pack2bf16(f1.z, f1.w);
  }
  __syncthreads();

  int lane = tid & 63;
  int wave = tid >> 6;
  int nodeBase = (blockIdx.x * 4 + wave) * 16;
  if (nodeBase >= N) return;
  int m = lane & 15;
  int kg = lane >> 4;

  short8 a[4];
  const float* xr = x + (size_t)(nodeBase + m) * DIM + kg * 8;
#pragma unroll
  for (int kt = 0; kt < 4; ++kt) {
    floatx4 f0 = *(const floatx4*)(xr + kt * 32);
    floatx4 f1 = *(const floatx4*)(xr + kt * 32 + 4);
    FragU fu;
    fu.d[0] = pack2bf16(f0.x, f0.y);
    fu.d[1] = pack2bf16(f0.z, f0.w);
    fu.d[2] = pack2bf16(f1.x, f1.y);
    fu.d[3] = pack2bf16(f1.z, f1.w);
    a[kt] = fu.s;
  }

#pragma unroll
  for (int ot = 0; ot < 8; ++ot) {
    int o = ot * 16 + m;
    floatx4 acc = {0.f, 0.f, 0.f, 0.f};
#pragma unroll
    for (int kt = 0; kt < 4; ++kt) {
      int slot = (kt * 4 + kg + o) & 15;
      short8 b = *(short8*)&Wl[o * DIM2 + slot * 4];
      acc = __builtin_amdgcn_mfma_f32_16x16x32_bf16(a[kt], b, acc, 0, 0, 0);
    }
#pragma unroll
    for (int r = 0; r < 4; ++r) {
      int node = nodeBase + kg * 4 + r;
      h[(size_t)node * DIM + ot * 16 + m] = (u16)f32_to_bf16_rne(acc[r]);
    }
  }
}

__global__ void zero_kernel(int* __restrict__ p, int n) {
  int i = blockIdx.x * blockDim.x + threadIdx.x;
  if (i < n) p[i] = 0;
}

// Exclusive scan over 2048 LDS counters with 256 threads (8 contiguous each).
__device__ __forceinline__ void scan2048(u32* cnt, u32* excl, u32* wtot) {
  int tid = threadIdx.x, lane = tid & 63, wave = tid >> 6;
  u32 c[8], sum = 0;
#pragma unroll
  for (int k = 0; k < 8; ++k) {
    c[k] = cnt[tid * 8 + k];
    sum += c[k];
  }
  u32 inc = sum;
#pragma unroll
  for (int d = 1; d < 64; d <<= 1) {
    u32 t = __shfl_up(inc, d, 64);
    if (lane >= d) inc += t;
  }
  if (lane == 63) wtot[wave] = inc;
  __syncthreads();
  u32 wbase = 0;
  for (int w = 0; w < wave; ++w) wbase += wtot[w];
  u32 run = wbase + inc - sum;
#pragma unroll
  for (int k = 0; k < 8; ++k) {
    excl[tid * 8 + k] = run;
    run += c[k];
  }
  __syncthreads();
}

// Global bucket histogram: LDS pre-aggregation, one global atomic per (WG,bucket).
__global__ __launch_bounds__(256) void bucket_hist(const int* __restrict__ rows,
                                                   int* __restrict__ bhist, int E, int B) {
  __shared__ u32 hist[NBK];
  int tid = threadIdx.x;
  for (int b = tid; b < NBK; b += 256) hist[b] = 0;
  __syncthreads();
  int base = blockIdx.x * HIST_C;
  for (int j = tid; j < HIST_C; j += 256) {
    int e = base + j;
    if (e < E) atomicAdd(&hist[((u32)rows[e]) >> NB_SH], 1u);
  }
  __syncthreads();
  for (int b = tid; b < B; b += 256) {
    u32 c = hist[b];
    if (c) atomicAdd(&bhist[b], (int)c);
  }
}

// One-WG exclusive scan of bucket counts -> bbase (agg reads) and bptr (scatter bumps).
__global__ __launch_bounds__(256) void bucket_scan(const int* __restrict__ bhist,
                                                   int* __restrict__ bbase,
                                                   int* __restrict__ bptr) {
  __shared__ u32 cnt[NBK], excl[NBK], wtot[4];
  int tid = threadIdx.x;
  for (int b = tid; b < NBK; b += 256) cnt[b] = (u32)bhist[b];
  __syncthreads();
  scan2048(cnt, excl, wtot);
  for (int b = tid; b < NBK; b += 256) {
    bbase[b] = (int)excl[b];
    bptr[b] = (int)excl[b];
  }
}

// LDS-binned perm scatter (R5 design) at 512 threads (grid-limited occupancy:
// 8-16 waves/CU vs R5's 4-8) and slimmer LDS (48 KB vs 64.5: gbase/roff folded
// into two arrays; off = gbase - starts stored in hist, starts doubles as the
// pass-2 running ptr).
__global__ __launch_bounds__(512) void bin_scatter(const int* __restrict__ rows,
                                                   const int* __restrict__ cols,
                                                   const float* __restrict__ vals,
                                                   int* __restrict__ bptr,
                                                   u32* __restrict__ bcol,
                                                   u16* __restrict__ bval, int E) {
  __shared__ u32 hist[NBK];    // counts -> off (gbase - starts0)
  __shared__ u32 starts[NBK];  // excl scan -> running ptr
  __shared__ u32 wtot[8];
  __shared__ u32 s_rec[SC_C];  // 32 KB perm
  int tid = threadIdx.x, lane = tid & 63, wv = tid >> 6;
  int base = blockIdx.x * SC_C;
  int tot = min(SC_C, E - base);

  for (int b = tid; b < NBK; b += 512) hist[b] = 0;
  __syncthreads();
  // pass 1: local histogram
  for (int j = tid; j < tot; j += 512) {
    atomicAdd(&hist[((u32)rows[base + j]) >> NB_SH], 1u);
  }
  __syncthreads();
  // scan 2048 counters with 512 threads (4 contiguous each)
  {
    u32 c[4], sum = 0;
#pragma unroll
    for (int k = 0; k < 4; ++k) {
      c[k] = hist[tid * 4 + k];
      sum += c[k];
    }
    u32 inc = sum;
#pragma unroll
    for (int d = 1; d < 64; d <<= 1) {
      u32 t = __shfl_up(inc, d, 64);
      if (lane >= d) inc += t;
    }
    if (lane == 63) wtot[wv] = inc;
    __syncthreads();
    u32 wbase = 0;
    for (int w = 0; w < wv; ++w) wbase += wtot[w];
    u32 run = wbase + inc - sum;
#pragma unroll
    for (int k = 0; k < 4; ++k) {
      starts[tid * 4 + k] = run;
      run += c[k];
    }
    __syncthreads();
  }
  // reserve global space; hist[b] becomes off = gbase - starts0
  for (int b = tid; b < NBK; b += 512) {
    u32 c = hist[b];
    u32 gb = c ? (u32)atomicAdd(&bptr[b], (int)c) : 0u;
    hist[b] = gb - starts[b];  // unsigned wrap ok
  }
  __syncthreads();
  // pass 2: rank packed perm records (bk<<19 | nl<<13 | j) into LDS
  for (int j = tid; j < tot; j += 512) {
    u32 r = (u32)rows[base + j];
    u32 bk = r >> NB_SH;
    u32 p = atomicAdd(&starts[bk], 1u);
    s_rec[p] = (bk << 19) | ((r & 63u) << 13) | (u32)j;
  }
  __syncthreads();
  // flush: bucket-sorted order -> near-coalesced runs; d = off + i
  for (int i = tid; i < tot; i += 512) {
    u32 rec = s_rec[i];
    u32 bk = rec >> 19;
    u32 nl = (rec >> 13) & 63u;
    int e = base + (int)(rec & 8191u);
    u32 d = hist[bk] + (u32)i;
    bcol[d] = (nl << 26) | ((u32)cols[e] << 8);
    bval[d] = (u16)f32_to_bf16_rne(vals[e]);
  }
}

// One WG per 64-node bucket (R5-exact structure, proven 123 us): whole bucket
// staged+sorted in LDS from its CONTIGUOUS global range (coalesced reads),
// flat walk with depth-8 gather pipeline, direct relu'd global flush. Only
// delta vs R5: s_rec u64 split into s_lo u32 + s_v u16 (LDS 20.8 -> 16 KB,
// 8 WG/CU).
__global__ __launch_bounds__(256) void agg_bucket(const int* __restrict__ bhist,
                                                  const int* __restrict__ bbase,
                                                  const u32* __restrict__ bcol,
                                                  const u16* __restrict__ bval,
                                                  const u32* __restrict__ h,
                                                  float* __restrict__ out, int N) {
  __shared__ u32 s_lo[AGG_CAP];  // 10 KB
  __shared__ u16 s_v[AGG_CAP];   // 5 KB
  __shared__ u32 cnt[AGG_NB], excl[AGG_NB], ptr[AGG_NB];
  int tid = threadIdx.x, lane = tid & 63, wave = tid >> 6;
  int b = blockIdx.x;
  int base = bbase[b], T = bhist[b];
  int nodeBase = b << NB_SH;
  int lane4 = lane * 4;
  const char* hb = (const char*)h;

  if (T <= AGG_CAP) {
    if (tid < AGG_NB) cnt[tid] = 0;
    __syncthreads();
    // pass A: coalesced bucket load (g = tid + 256*k) + node histogram
    u32 rlo[10], rv[10];
#pragma unroll
    for (int k = 0; k < 10; ++k) {
      int g = tid + 256 * k;
      rlo[k] = 0;
      rv[k] = 0;
      if (g < T) {
        rlo[k] = bcol[base + g];
        rv[k] = bval[base + g];
        atomicAdd(&cnt[rlo[k] >> 26], 1u);
      }
    }
    __syncthreads();
    if (tid < 64) {
      u32 c = cnt[tid], inc = c;
#pragma unroll
      for (int d = 1; d < 64; d <<= 1) {
        u32 t = __shfl_up(inc, d, 64);
        if (lane >= d) inc += t;
      }
      excl[tid] = inc - c;
      ptr[tid] = inc - c;
    }
    __syncthreads();
    // pass B: rank into node-sorted LDS staging
#pragma unroll
    for (int k = 0; k < 10; ++k) {
      int g = tid + 256 * k;
      if (g < T) {
        u32 p = atomicAdd(&ptr[rlo[k] >> 26], 1u);
        s_lo[p] = rlo[k];
        s_v[p] = (u16)rv[k];
      }
    }
    __syncthreads();
    // pass C: flat walk of my wave's 16 nodes' contiguous segment
    int wbeg = (int)excl[wave * 16];
    int wend = (int)ptr[wave * 16 + 15];
    float a0 = 0.f, a1 = 0.f;
    int curn = -1;
    for (int e = wbeg; e < wend; e += 8) {
      u32 lo8[8];
      float v8[8];
      u32 hd[8];
#pragma unroll
      for (int g = 0; g < 8; ++g) {
        int ee = e + g;
        bool act = ee < wend;
        int idx = act ? ee : (wend - 1);  // wave-uniform broadcast reads
        lo8[g] = s_lo[idx];
        v8[g] = act ? bf16_to_f32((u32)s_v[idx]) : 0.f;
      }
#pragma unroll
      for (int g = 0; g < 8; ++g) {
        hd[g] = *(const u32*)(hb + ((lo8[g] & 0x01FFFF00u) + lane4));
      }
#pragma unroll
      for (int g = 0; g < 8; ++g) {
        int nid = __builtin_amdgcn_readfirstlane((int)(lo8[g] >> 26));
        if (nid != curn) {  // scalar branch, once per run
          if (curn >= 0) {
            float2 o = make_float2(fmaxf(a0, 0.f), fmaxf(a1, 0.f));
            *(float2*)(out + (size_t)(nodeBase + curn) * DIM + 2 * lane) = o;
          }
          curn = nid;
          a0 = 0.f;
          a1 = 0.f;
        }
        float v = v8[g];
        a0 += v * bf16_to_f32(hd[g] & 0xffffu);
        a1 += v * bf16_to_f32(hd[g] >> 16);
      }
    }
    if (curn >= 0) {
      float2 o = make_float2(fmaxf(a0, 0.f), fmaxf(a1, 0.f));
      *(float2*)(out + (size_t)(nodeBase + curn) * DIM + 2 * lane) = o;
    }
    // epilogue: zero rows for nodes with no edges
    for (int nn = 0; nn < 16; ++nn) {
      int nl = wave * 16 + nn;
      int node = nodeBase + nl;
      if (cnt[nl] == 0 && node < N) {
        *(float2*)(out + (size_t)node * DIM + 2 * lane) = make_float2(0.f, 0.f);
      }
    }
  } else {
    // Guaranteed-correct fallback (statistically unreachable): per-node scan
    // of the bucket's contiguous edge range.
    for (int nn = 0; nn < 16; ++nn) {
      int nl = wave * 16 + nn;
      int node = nodeBase + nl;
      if (node >= N) continue;
      float a0 = 0.f, a1 = 0.f;
      for (int e = 0; e < T; ++e) {
        u32 lo = bcol[base + e];
        if ((int)(lo >> 26) == nl) {
          u32 d = *(const u32*)(hb + ((lo & 0x01FFFF00u) + lane4));
          float v = bf16_to_f32(bval[base + e]);
          a0 += v * bf16_to_f32(d & 0xffffu);
          a1 += v * bf16_to_f32(d >> 16);
        }
      }
      *(float2*)(out + (size_t)node * DIM + 2 * lane) =
          make_float2(fmaxf(a0, 0.f), fmaxf(a1, 0.f));
    }
  }
}

extern "C" void kernel_launch(void* const* d_in, const int* in_sizes, int n_in,
                              void* d_out, int out_size, void* d_ws, size_t ws_size,
                              hipStream_t stream) {
  const float* x    = (const float*)d_in[0];  // fp32 [N,128]
  const int*   rows = (const int*)d_in[1];    // int32 [E]
  const int*   cols = (const int*)d_in[2];    // int32 [E]
  const float* vals = (const float*)d_in[3];  // fp32 [E]
  const float* W    = (const float*)d_in[4];  // fp32 [128,128]

  const int N = in_sizes[0] / DIM;  // 100000
  const int E = in_sizes[1];        // 3200000
  const int B = (N + AGG_NB - 1) / AGG_NB;  // 1563 buckets

  char* wsb = (char*)d_ws;
  size_t o = 0;
  u16* h = (u16*)wsb;                    o += (size_t)N * DIM * sizeof(u16);  // 25.6 MB
  int* bhist = (int*)(wsb + o);          o += (size_t)NBK * 4;
  int* bbase = (int*)(wsb + o);          o += (size_t)NBK * 4;
  int* bptr  = (int*)(wsb + o);          o += (size_t)NBK * 4;
  u32* bcol  = (u32*)(wsb + o);          o += (size_t)E * 4;                  // 12.8 MB
  u16* bval  = (u16*)(wsb + o);          o += (size_t)E * 2;                  // 6.4 MB

  const int nhist = (E + HIST_C - 1) / HIST_C;  // 782
  const int nsc = (E + SC_C - 1) / SC_C;        // 391

  zero_kernel<<<(NBK + 255) / 256, 256, 0, stream>>>(bhist, NBK);
  gemm_mfma<<<(N + 63) / 64, 256, 0, stream>>>(x, W, h, N);
  bucket_hist<<<nhist, 256, 0, stream>>>(rows, bhist, E, B);
  bucket_scan<<<1, 256, 0, stream>>>(bhist, bbase, bptr);
  bin_scatter<<<nsc, 512, 0, stream>>>(rows, cols, vals, bptr, bcol, bval, E);
  agg_bucket<<<B, 256, 0, stream>>>(bhist, bbase, bcol, bval, (const u32*)h,
                                    (float*)d_out, N);
}